// Round 30
// baseline (25.341 us; speedup 1.0000x reference)
//
#include <hip/hip_runtime.h>

typedef _Float16 f16x8 __attribute__((ext_vector_type(8)));
typedef _Float16 f16x4 __attribute__((ext_vector_type(4)));
typedef _Float16 f16x2 __attribute__((ext_vector_type(2)));
typedef float    f32x4 __attribute__((ext_vector_type(4)));

#define NPTS   385
#define GLMIN  (-6.0f)
#define INVH   32.0f
#define NVIRT  (170 * NPTS)

__device__ unsigned g_tab[2 * 170 * 5 * NPTS];   // f16x2 (o0,o1) curves, 2.62 MB

// ---- build-kernel LDS f16 region (halfword offsets) ----
#define L_PRE   0                    // [3][64]   pre-rows for the block's champs
#define L_W1    192                  // [64]
#define L_W2    256                  // [32][72]
#define L_W3    2560                 // [16][40]
#define L_WFR   3200                 // [5][40]
#define L_END   3400
#define LF_B2   0
#define LF_B3   32

__device__ __forceinline__ f16x8 hfma8(f16x8 a, f16x8 b, f16x8 c) {
    return __builtin_elementwise_fma(a, b, c);
}
__device__ __forceinline__ f16x8 hrelu8(f16x8 a) {
    const f16x8 z = {0, 0, 0, 0, 0, 0, 0, 0};
    return __builtin_elementwise_max(a, z);
}
__device__ __forceinline__ f16x4 hrelu4(f16x4 a) {
    const f16x4 z = {0, 0, 0, 0};
    return __builtin_elementwise_max(a, z);
}
__device__ __forceinline__ f16x2 pkrtz(float a, float b) {
    return __builtin_bit_cast(f16x2, __builtin_amdgcn_cvt_pkrtz(a, b));
}

// Final kernel (= round 29): piecewise-linear table method.
//   build_all: 256 co-resident blocks; each stages weights once, computes its
//     champs' pre-rows, builds the 2.62 MB (team,champ,slot) x gl-grid table
//     with the MFMA slot engine (4 chunks of 128 virtual points per block).
//   table_main: 1 thread = 1 sample; 10 independent 8B L2 gathers + f32 lerp.
// Exactness: out(gl) is piecewise-linear in gl (ReLU MLP, input affine in
// gl), so lerp is exact away from knees; knee cells err ~4e-4 at h=1/32.
// 846us (r1 naive) -> 24.8us over the session; remaining budget: ~5us L2
// gather floor + ~4us build + ~5us launch boundaries. All structural levers
// (fusion, boundary removal, staging amortization, gather widening) tested.
__global__ __launch_bounds__(512)
__attribute__((amdgpu_waves_per_eu(4, 4)))
void build_all(const float* __restrict__ emb,
               const float* __restrict__ W1a, const float* __restrict__ b1a,
               const float* __restrict__ W2a, const float* __restrict__ b2a,
               const float* __restrict__ W3a, const float* __restrict__ b3a,
               const float* __restrict__ W1b, const float* __restrict__ b1b,
               const float* __restrict__ W2b, const float* __restrict__ b2b,
               const float* __restrict__ W3b, const float* __restrict__ b3b,
               const float* __restrict__ Wf)
{
    __shared__ float sW1[2550];
    __shared__ float sE[3][52];
    __shared__ __align__(16) _Float16 sm16[L_END];
    __shared__ __align__(16) float    smf[48];

    const int tid = threadIdx.x;
    const int team = blockIdx.y;
    const float* __restrict__ W1 = team ? W1b : W1a;
    const float* __restrict__ B1 = team ? b1b : b1a;
    const float* __restrict__ W2 = team ? W2b : W2a;
    const float* __restrict__ B2 = team ? b2b : b2a;
    const float* __restrict__ W3 = team ? W3b : W3a;
    const float* __restrict__ B3 = team ? b3b : b3a;

    const int vbase = blockIdx.x * 512;
    const int champ_lo = vbase / NPTS;

    for (int i = tid; i < 2550; i += 512) sW1[i] = W1[i];
    for (int i = tid; i < 3 * 50; i += 512) {
        const int cc = i / 50, d = i % 50;
        int ch = champ_lo + cc;
        if (ch > 169) ch = 169;
        sE[cc][d] = emb[ch * 50 + d];
    }
    for (int i = tid; i < 64; i += 512)
        sm16[L_W1 + i] = (_Float16)((i < 50) ? W1[i * 51 + 50] : 0.0f);
    for (int i = tid; i < 32 * 64; i += 512) {
        const int m = i >> 6, k = i & 63;
        sm16[L_W2 + m * 72 + k] =
            (_Float16)((m < 25 && k < 50) ? W2[m * 50 + k] : 0.0f);
    }
    for (int i = tid; i < 16 * 32; i += 512) {
        const int t = i >> 5, m = i & 31;
        sm16[L_W3 + t * 40 + m] =
            (_Float16)((t < 10 && m < 25) ? W3[t * 25 + m] : 0.0f);
    }
    for (int i = tid; i < 5 * 32; i += 512) {
        const int s = i >> 5, r = (i >> 4) & 1, k = i & 15;
        sm16[L_WFR + s * 40 + r * 16 + k] =
            (_Float16)((k < 10) ? Wf[r * 100 + team * 50 + s * 10 + k] : 0.0f);
    }
    for (int i = tid; i < 32; i += 512) smf[LF_B2 + i] = (i < 25) ? B2[i] : 0.0f;
    for (int i = tid; i < 16; i += 512) smf[LF_B3 + i] = (i < 10) ? B3[i] : 0.0f;
    __syncthreads();

    for (int i = tid; i < 192; i += 512) {
        const int cc = i >> 6, k = i & 63;
        float v = 0.0f;
        if (k < 50) {
            v = B1[k];
            const float* __restrict__ wr = sW1 + k * 51;
            #pragma unroll 5
            for (int d = 0; d < 50; ++d)
                v = fmaf(wr[d], sE[cc][d], v);
        }
        sm16[L_PRE + cc * 64 + k] = (_Float16)v;
    }
    __syncthreads();

    const int l  = tid & 63;
    const int c  = l & 15;
    const int g  = l >> 4;
    const int wv = tid >> 6;

    f16x8 w2A[2][2];
    #pragma unroll
    for (int mt = 0; mt < 2; ++mt)
        #pragma unroll
        for (int kf = 0; kf < 2; ++kf)
            w2A[mt][kf] = *(const f16x8*)(sm16 + L_W2 + (mt * 16 + c) * 72
                                          + kf * 32 + g * 8);
    const f16x4 w3A0 = *(const f16x4*)(sm16 + L_W3 + c * 40 + 4 * g);
    const f16x4 w3A1 = *(const f16x4*)(sm16 + L_W3 + c * 40 + 16 + 4 * g);
    const f16x8 w1gA = *(const f16x8*)(sm16 + L_W1 + g * 8);
    const f16x8 w1gB = *(const f16x8*)(sm16 + L_W1 + 32 + g * 8);
    const f32x4 b2lo = *(const f32x4*)(smf + LF_B2 + 4 * g);
    const f32x4 b2hi = *(const f32x4*)(smf + LF_B2 + 16 + 4 * g);
    const f32x4 b3v  = *(const f32x4*)(smf + LF_B3 + 4 * g);
    f16x4 wfrAll = {0, 0, 0, 0};
    if (c < 10)
        wfrAll = *(const f16x4*)(sm16 + L_WFR + (c >> 1) * 40 + (c & 1) * 16 + 4 * g);
    const f32x4 zero4 = {0.f, 0.f, 0.f, 0.f};

    #pragma clang loop unroll(disable)
    for (int ck = 0; ck < 4; ++ck) {
        const int v = vbase + ck * 128 + wv * 16 + c;
        const bool valid = v < NVIRT;
        const int vE = valid ? v : (NVIRT - 1);
        const int champ = vE / NPTS, ip = vE - champ * NPTS;
        const int dch = champ - champ_lo;
        const float gl = GLMIN + (float)ip * (1.0f / INVH);

        const _Float16 glh = (_Float16)gl;
        const f16x8 glv = {glh, glh, glh, glh, glh, glh, glh, glh};

        const f16x8 pc0 = *(const f16x8*)(sm16 + L_PRE + dch * 64 + g * 8);
        const f16x8 pc1 = *(const f16x8*)(sm16 + L_PRE + dch * 64 + 32 + g * 8);

        const f16x8 h10 = hrelu8(hfma8(w1gA, glv, pc0));
        const f16x8 h11 = hrelu8(hfma8(w1gB, glv, pc1));

        f32x4 a0  = __builtin_amdgcn_mfma_f32_16x16x32_f16(w2A[0][0], h10, b2lo,  0, 0, 0);
        f32x4 a0x = __builtin_amdgcn_mfma_f32_16x16x32_f16(w2A[0][1], h11, zero4, 0, 0, 0);
        f32x4 a1  = __builtin_amdgcn_mfma_f32_16x16x32_f16(w2A[1][0], h10, b2hi,  0, 0, 0);
        f32x4 a1x = __builtin_amdgcn_mfma_f32_16x16x32_f16(w2A[1][1], h11, zero4, 0, 0, 0);
        a0 = a0 + a0x;
        a1 = a1 + a1x;

        const f16x2 p00 = pkrtz(a0[0], a0[1]);
        const f16x2 p01 = pkrtz(a0[2], a0[3]);
        const f16x2 p10 = pkrtz(a1[0], a1[1]);
        const f16x2 p11 = pkrtz(a1[2], a1[3]);
        const f16x4 b3t0 = hrelu4((f16x4){p00.x, p00.y, p01.x, p01.y});
        const f16x4 b3t1 = hrelu4((f16x4){p10.x, p10.y, p11.x, p11.y});

        f32x4 a3  = __builtin_amdgcn_mfma_f32_16x16x16f16(w3A0, b3t0, b3v,   0, 0, 0);
        f32x4 a3x = __builtin_amdgcn_mfma_f32_16x16x16f16(w3A1, b3t1, zero4, 0, 0, 0);
        a3 = a3 + a3x;

        const f16x2 q0 = pkrtz(a3[0], a3[1]);
        const f16x2 q1 = pkrtz(a3[2], a3[3]);
        const f16x4 h3f = hrelu4((f16x4){q0.x, q0.y, q1.x, q1.y});

        const f32x4 a4 = __builtin_amdgcn_mfma_f32_16x16x16f16(wfrAll, h3f, zero4, 0, 0, 0);

        if (valid && g <= 2) {
            const int ebase = (team * 170 + champ) * 5;
            f16x2 pA;
            pA.x = (_Float16)a4[0];
            pA.y = (_Float16)a4[1];
            g_tab[(ebase + 2 * g) * NPTS + ip] = __builtin_bit_cast(unsigned, pA);
            if (g <= 1) {
                f16x2 pB;
                pB.x = (_Float16)a4[2];
                pB.y = (_Float16)a4[3];
                g_tab[(ebase + 2 * g + 1) * NPTS + ip] = __builtin_bit_cast(unsigned, pB);
            }
        }
    }
}

__global__ __launch_bounds__(256)
void table_main(const float* __restrict__ feat, const float* __restrict__ bf,
                float2* __restrict__ out, int nB)
{
    const int s = blockIdx.x * 256 + threadIdx.x;
    if (s >= nB) return;
    const float4* f4 = reinterpret_cast<const float4*>(feat + (size_t)s * 12);
    const float4 v0 = f4[0], v1 = f4[1], v2 = f4[2];
    const float fr_[12] = {v0.x, v0.y, v0.z, v0.w, v1.x, v1.y, v1.z, v1.w,
                           v2.x, v2.y, v2.z, v2.w};

    int   iT[2];
    float fT[2];
    #pragma unroll
    for (int team = 0; team < 2; ++team) {
        const float u = (fr_[team] - GLMIN) * INVH;
        int i = (int)u;
        i = (i < 0) ? 0 : ((i > NPTS - 2) ? NPTS - 2 : i);
        float f = u - (float)i;
        f = fminf(fmaxf(f, 0.0f), 1.0f);
        iT[team] = i;
        fT[team] = f;
    }

    float o0 = bf[0], o1 = bf[1];
    #pragma unroll
    for (int sl = 0; sl < 10; ++sl) {
        const int team = sl / 5;
        const int ci = (int)fr_[2 + sl];
        const unsigned* __restrict__ p =
            g_tab + ((team * 170 + ci) * 5 + (sl - team * 5)) * NPTS + iT[team];
        const f16x2 ha = __builtin_bit_cast(f16x2, p[0]);
        const f16x2 hb = __builtin_bit_cast(f16x2, p[1]);
        const float a0 = (float)ha.x, a1 = (float)ha.y;
        const float b0 = (float)hb.x, b1 = (float)hb.y;
        o0 += fmaf(fT[team], b0 - a0, a0);
        o1 += fmaf(fT[team], b1 - a1, a1);
    }
    out[s] = make_float2(o0, o1);
}

extern "C" void kernel_launch(void* const* d_in, const int* in_sizes, int n_in,
                              void* d_out, int out_size, void* d_ws, size_t ws_size,
                              hipStream_t stream) {
    const float* feat = (const float*)d_in[0];
    const float* emb  = (const float*)d_in[1];
    const float* W1a  = (const float*)d_in[2];
    const float* b1a  = (const float*)d_in[3];
    const float* W2a  = (const float*)d_in[4];
    const float* b2a  = (const float*)d_in[5];
    const float* W3a  = (const float*)d_in[6];
    const float* b3a  = (const float*)d_in[7];
    const float* W1b  = (const float*)d_in[8];
    const float* b1b  = (const float*)d_in[9];
    const float* W2b  = (const float*)d_in[10];
    const float* b2b  = (const float*)d_in[11];
    const float* W3b  = (const float*)d_in[12];
    const float* b3b  = (const float*)d_in[13];
    const float* Wf   = (const float*)d_in[14];
    const float* bf   = (const float*)d_in[15];
    const int nB = in_sizes[0] / 12;

    const int vblocks = (NVIRT + 511) / 512;           // 128
    build_all<<<dim3(vblocks, 2), 512, 0, stream>>>(emb,
        W1a, b1a, W2a, b2a, W3a, b3a,
        W1b, b1b, W2b, b2b, W3b, b3b, Wf);

    table_main<<<(nB + 255) / 256, 256, 0, stream>>>(feat, bf, (float2*)d_out, nB);
}